// Round 8
// baseline (440.929 us; speedup 1.0000x reference)
//
#include <hip/hip_runtime.h>

typedef unsigned short u16;
typedef unsigned int   u32;

#define NTOK 294
#define KS_STRIDE 34
#define VT_STRIDE 300
#define WST 260
#define OBUF_BYTES 38535168ull   // old path: 256*294*256 u16
#define FLAG_OFF (OBUF_BYTES)    // old path flag location (proven to fit)

// ---- new-path workspace layout (bytes) ----
#define ROWS_ALLOC 75280ull                      // 75264 rows + 16 slack
#define BUFB (ROWS_ALLOC * 512ull)               // 38,543,360 per f16 [rows][256] buffer
#define QWS_OFF   0ull
#define KWS_OFF   (QWS_OFF + BUFB)
#define VWS_OFF   (KWS_OFF + BUFB)
#define OWS_OFF   (VWS_OFF + BUFB)
#define BIASF_OFF (OWS_OFF + BUFB)               // f32 [8][19][304][16] = 2,957,312
#define BIASF_BYTES 2957312ull
#define WQT_OFF   (BIASF_OFF + BIASF_BYTES)      // 768*256 f16  = 393,216
#define WOT_OFF   (WQT_OFF + 393216ull)          // 256*256 f16  = 131,072
#define FLAG2_OFF (WOT_OFF + 131072ull)
#define NEED_WS   (FLAG2_OFF + 4ull)             // ~157.7 MB

typedef __fp16 hv2  __attribute__((ext_vector_type(2)));
typedef __fp16 f16x4 __attribute__((ext_vector_type(4)));
typedef __fp16 f16x8 __attribute__((ext_vector_type(8)));
typedef float  f32x4 __attribute__((ext_vector_type(4)));

__device__ __forceinline__ float b2f(u16 v){ union{u32 u; float f;} x; x.u = ((u32)v) << 16; return x.f; }
__device__ __forceinline__ u16 f2b(float f){
  union{float f; u32 u;} x; x.f = f; u32 u = x.u;
  return (u16)((u + 0x7fffu + ((u >> 16) & 1u)) >> 16);      // RTNE bf16
}
__device__ __forceinline__ u32 pack2h(float a, float b){
#if __has_builtin(__builtin_amdgcn_cvt_pkrtz)
  auto r = __builtin_amdgcn_cvt_pkrtz(a, b);
  union{ decltype(r) h; u32 u; } x; x.h = r; return x.u;
#else
  union{ hv2 h; u32 u; } x; x.h[0] = (__fp16)a; x.h[1] = (__fp16)b; return x.u;
#endif
}
__device__ __forceinline__ u32 bfp2h(u32 bfp){
  union{u32 u; float f;} lo, hi; lo.u = bfp << 16; hi.u = bfp & 0xffff0000u;
  return pack2h(lo.f, hi.f);
}
__device__ __forceinline__ u16 f2h(float a){ return (u16)(pack2h(a, 0.0f) & 0xffffu); }

__device__ __forceinline__ float dot2f(u32 a, u32 b, float c){
#if __has_builtin(__builtin_amdgcn_fdot2)
  union{u32 u; hv2 h;} A, B; A.u = a; B.u = b;
  return __builtin_amdgcn_fdot2(A.h, B.h, c, false);
#else
  union{u32 u; __fp16 h[2];} A, B; A.u = a; B.u = b;
  return c + (float)A.h[0]*(float)B.h[0] + (float)A.h[1]*(float)B.h[1];
#endif
}

// raw HW 2^x (single v_exp_f32). Logits are pre-scaled by log2e in prep,
// so softmax in the exp2 domain is mathematically identical.
__device__ __forceinline__ float fexp2(float x){
#if __has_builtin(__builtin_amdgcn_exp2f)
  return __builtin_amdgcn_exp2f(x);
#else
  return exp2f(x);
#endif
}

__device__ __forceinline__ f32x4 mfma16(f16x8 a, f16x8 b, f32x4 c){
  return __builtin_amdgcn_mfma_f32_16x16x32_f16(a, b, c, 0, 0, 0);
}
// K=16 variant: A,B = 4 f16 (2 VGPR). Lane (q,n16): A row=n16 k=q*4+e;
// B col=n16 k=q*4+e; C/D same as 16x16x32 (col=lane&15, row=q*4+reg).
__device__ __forceinline__ f32x4 mfma16k16(f16x4 a, f16x4 b, f32x4 c){
  return __builtin_amdgcn_mfma_f32_16x16x16f16(a, b, c, 0, 0, 0);
}

// async global->LDS, 16B per lane. LDS dest is wave-uniform base + lane*16
// (m104) -> dest must be linear; swizzling is done on the GLOBAL source
// addresses + the LDS read side (T21: both-sides-or-neither).
__device__ __forceinline__ void gl2lds16(const void* g, void* l){
#if __has_builtin(__builtin_amdgcn_global_load_lds)
  __builtin_amdgcn_global_load_lds(
      (const __attribute__((address_space(1))) void*)g,
      (__attribute__((address_space(3))) void*)l, 16, 0, 0);
#else
  *(f16x8*)l = *(const f16x8*)g;
#endif
}

// Stage one 16x256-f16 B tile (8 KB) into LDS, double-buffer slot `buf`.
// Source granules pre-swizzled with g ^= (row&7) so the swizzled ds_read
// (bank-conflict-free for the (n16,q) fragment pattern) sees correct data.
__device__ __forceinline__ void stageB(const u16* __restrict__ wsrc, int nt,
                                       u16* lbase, int wave, int lane){
#pragma unroll
  for (int c = 0; c < 2; ++c){
    int G   = (c*4 + wave)*64 + lane;           // granule 0..511 (16B units)
    int row = G >> 5, g = G & 31;
    int sg  = g ^ (row & 7);
    const u16* src = wsrc + (size_t)nt*4096 + row*256 + sg*8;
    u16* dst = lbase + (size_t)(c*4 + wave)*512;
    gl2lds16(src, dst);
  }
}

// swizzled B fragment read: B[n16][ks*32+q*8] lives at granule (ks*4+q)^(n16&7)
__device__ __forceinline__ f16x8 readB(const u16* bb, int ks, int q, int n16){
  return *(const f16x8*)&bb[n16*256 + (((ks*4 + q) ^ (n16 & 7)) * 8)];
}

// -------------------------------------------------------------------------
// Probe: bf16 (flag 0) vs f32 (flag 1) input dtype, from exponent stats.
// -------------------------------------------------------------------------
__global__ void dfab_probe_kernel(const u16* __restrict__ X, int* __restrict__ flag)
{
  const int lane = threadIdx.x;   // 64 threads
  int cnt = 0;
#pragma unroll
  for (int k = 0; k < 8; ++k){
    u16 v = X[lane * 8 + k];
    int e = (v >> 7) & 0xFF;
    cnt += (e < 96 || e > 158) ? 1 : 0;
  }
  for (int off = 32; off > 0; off >>= 1) cnt += __shfl_xor(cnt, off);
  if (lane == 0) *flag = (cnt > 64) ? 1 : 0;
}

// =========================================================================
// NEW PATH
// =========================================================================

// prep: WqkvT[n][k] f16 (Q-scaled), WoutT[n][k] f16,
// Biasf f32 [h][mt][col][16rows] (log2e-folded, R7 tiled layout: attn2's
// per-m-tile bias init becomes one dwordx4 + 4 adds per tile).
__global__ __launch_bounds__(256) void dfab_prep_kernel(
    const void* __restrict__ Wqkvv, const void* __restrict__ Woutv,
    const void* __restrict__ BiasTv, const int* __restrict__ RelIdx,
    u16* __restrict__ wqt, u16* __restrict__ wot, float* __restrict__ biasf,
    const int* __restrict__ flagp)
{
  const int f32m = *(const volatile int*)flagp;
  const u16* Wb = (const u16*)Wqkvv;  const float* Wf = (const float*)Wqkvv;
  const u16* Ob = (const u16*)Woutv;  const float* Of = (const float*)Woutv;
  const u16* Bb = (const u16*)BiasTv; const float* Bf = (const float*)BiasTv;
  int idx = blockIdx.x * 256 + threadIdx.x;          // grid 3912 -> 1,001,472
  if (idx < 196608){
    int n = idx >> 8, k = idx & 255;
    float w = f32m ? Wf[k*768 + n] : b2f(Wb[k*768 + n]);
    if (n < 256) w *= 0.25503487f;                   // dh^-0.5 * log2(e)
    wqt[n*256 + k] = f2h(w);
  } else if (idx < 262144){
    int t = idx - 196608; int n = t >> 8, k = t & 255;
    float w = f32m ? Of[k*256 + n] : b2f(Ob[k*256 + n]);
    wot[n*256 + k] = f2h(w);
  } else {
    int t = idx - 262144;                            // 739,328 = 8*19*304*16
    int hh = t / 92416; int rem = t - hh * 92416;    // 92416 = 19*304*16
    int mt = rem / 4864; int r2 = rem - mt * 4864;   // 4864 = 304*16
    int col = r2 >> 4;  int rw = r2 & 15;
    int i = mt * 16 + rw;                            // row (query token)
    float v = 0.f;
    if (i < NTOK && col < NTOK){
      int nb = RelIdx[i * NTOK + col] * 8 + hh;
      v = (f32m ? Bf[nb] : b2f(Bb[nb])) * 1.4426950409f;   // log2(e)
    }
    biasf[((size_t)((hh*19 + mt)*304 + col))*16 + rw] = v;
  }
}

// QKV GEMM: rows m = win*294+tok (M=75264), K=256, N=768 -> Q/K/V f16 ws
// R3 restructure (confirmed: qkv left top-5, total 626->416): LDS-staged B
// via global_load_lds (dbuf, shared by 4 waves), swizzled ds_read_b128
// fragments, C coalesced through per-wave LDS tile into dwordx4 stores.
__global__ __launch_bounds__(256, 4) void dfab_qkv_kernel(
    const void* __restrict__ Xv, const u16* __restrict__ wqt,
    u16* __restrict__ Qws, u16* __restrict__ Kws, u16* __restrict__ Vws,
    const int* __restrict__ flagp)
{
  __shared__ __align__(16) union {
    u16 xs[64 * 264];                        // 33,792 B (staging phase)
    struct { u16 bs[2][4096]; u16 cs[4][1024]; } p;  // 16K + 8K (loop phase)
  } sm;

  const int tid = threadIdx.x;
  const int m0 = blockIdx.x * 64;
  const int f32m = *(const volatile int*)flagp;
  const u16* Xb = (const u16*)Xv; const float* Xf = (const float*)Xv;
  const int wave = tid >> 6, lane = tid & 63;
  const int q = lane >> 4, n16 = lane & 15;

  // ---- phase 1: stage X rows into xs, load A fragments ----
  for (int idx = tid; idx < 64 * 128; idx += 256){
    int rl = idx >> 7, d2 = idx & 127;
    int m = m0 + rl; int win = m / 294, tok = m - win * 294;
    int l = tok / 49, r = tok - l * 49;
    size_t src = ((size_t)((l*256 + win)*49 + r))*256 + 2*d2;
    u32 hp;
    if (f32m){ float2 xx = *(const float2*)&Xf[src]; hp = pack2h(xx.x, xx.y); }
    else     { hp = bfp2h(*(const u32*)&Xb[src]); }
    *(u32*)&sm.xs[rl * 264 + 2*d2] = hp;
  }
  __syncthreads();

  f16x8 afr[8];
#pragma unroll
  for (int ks = 0; ks < 8; ++ks)
    afr[ks] = *(const f16x8*)&sm.xs[(wave*16 + n16) * 264 + ks*32 + q*8];
  __syncthreads();                       // all afr reads done before xs is overwritten

  // ---- phase 2: B-tile loop (bs/cs overlay xs) ----
  stageB(wqt, 0, &sm.p.bs[0][0], wave, lane);
  __syncthreads();                       // bs[0] landed (barrier drains vmcnt)

  u16* myC = &sm.p.cs[wave][0];
  const size_t rowb = (size_t)(m0 + wave*16);
  const int rbrow = lane >> 3, seg = lane & 7;

#pragma unroll 1
  for (int grp = 0; grp < 12; ++grp){
    u16* dstp = (grp < 4) ? Qws : ((grp < 8) ? Kws : Vws);
    const int g4 = grp & 3;
#pragma unroll
    for (int t = 0; t < 4; ++t){
      const int nt = grp*4 + t;
      if (nt < 47) stageB(wqt, nt+1, &sm.p.bs[(nt+1)&1][0], wave, lane);
      const u16* bb = &sm.p.bs[nt&1][0];
      f16x8 bfr[8];
#pragma unroll
      for (int ks = 0; ks < 8; ++ks) bfr[ks] = readB(bb, ks, q, n16);
      f32x4 c0 = {0.f,0.f,0.f,0.f}, c1 = {0.f,0.f,0.f,0.f};
#pragma unroll
      for (int ks = 0; ks < 4; ++ks){
        c0 = mfma16(afr[ks],     bfr[ks],     c0);
        c1 = mfma16(afr[ks + 4], bfr[ks + 4], c1);
      }
#pragma unroll
      for (int r = 0; r < 4; ++r)
        myC[(q*4 + r)*64 + t*16 + n16] = f2h(c0[r] + c1[r]);
      __syncthreads();                   // bs[(nt+1)&1] landed; cs writes drained
    }
    // wide coalesced C store: 16 rows x 128 B per wave, dwordx4 per lane
    __asm__ volatile("s_waitcnt lgkmcnt(0)" ::: "memory");
#pragma unroll
    for (int p = 0; p < 2; ++p){
      const int row = p*8 + rbrow;
      f16x8 v = *(const f16x8*)&myC[row*64 + seg*8];
      *(f16x8*)&dstp[(rowb + row)*256 + g4*64 + seg*8] = v;
    }
  }
}

// Attention: block=(win,head); waves own independent 16-row m-tiles.
// R1 (rule #20): all S indices compile-time -> S in VGPRs.
// R4 (confirmed): K in LDS Ks[304x40], V^T in Vt, wide staging loads.
// R5 FAILED: kf in regs -> rematerialized. Only LDS staging pins placement.
// R6: exp2-domain softmax (kept; exp was NOT the VALU hog - theory refuted).
// R7: (a) PV per-tile pipeline with K=16 MFMA + double-buffered 16x20 P-tile:
// no lgkmcnt(0) drains (per-wave DS is in-order -> WAR safe; compiler emits
// counted lgkmcnt for RAW). (b) LDS 68->51.6KB -> 3 blocks/CU (Occupancy
// was 20%). (c) f32 tiled bias: dwordx4 + 4 adds per tile (was cvt+addr).
__global__ __launch_bounds__(256, 3) void dfab_attn2_kernel(
    const u16* __restrict__ Qws, const u16* __restrict__ Kws,
    const u16* __restrict__ Vws, const float* __restrict__ Biasf,
    const int* __restrict__ Mask, u16* __restrict__ Ows)
{
  __shared__ __align__(16) u16 Ks[304 * 40];         // 24,320 B (stride 40 u16 = 80 B)
  __shared__ __align__(16) u16 Vt[32 * 328];         // 20,992 B (stride 328)
  __shared__ __align__(16) u16 Pt[4][2][16 * 20];    // 5,120 B (2-slot dbuf per wave)
  __shared__ float Madd[304];

  const int tid = threadIdx.x;
  const int win = blockIdx.x >> 3, h = blockIdx.x & 7;
  const int wave = tid >> 6, lane = tid & 63;
  const int q = lane >> 4, n16 = lane & 15;

  for (int j = tid; j < 304; j += 256){
    float mv = -1e30f;
    if (j < NTOK){ int l = j / 49, r = j - l * 49;
      mv = (Mask[(win * 49 + r) * 6 + l] != 0) ? 0.0f : -1e30f; }
    Madd[j] = mv;
  }

  // stage K -> Ks[row][32] (16B per (row,seg)); zero pad rows 294..303.
  {
    const int rr0 = tid >> 2, seg = tid & 3;
#pragma unroll
    for (int p = 0; p < 5; ++p){
      int rr = rr0 + p*64;
      if (rr < NTOK){
        f16x8 kv = *(const f16x8*)&Kws[((size_t)(win*NTOK + rr))*256 + h*32 + seg*8];
        *(f16x8*)&Ks[rr*40 + seg*8] = kv;
      }
    }
    if (tid < 40){
      int rr = NTOK + (tid >> 2);
      uint4 z = {0u,0u,0u,0u};
      *(uint4*)&Ks[rr*40 + seg*8] = z;
    }
    // stage V -> Vt[c][tok] transpose, 16B vector loads (tok<320 zero-fill)
#pragma unroll
    for (int p = 0; p < 5; ++p){
      int tok = rr0 + p*64;                          // 0..319
      union{ f16x8 h; u16 s[8]; } vv;
      uint4 z = {0u,0u,0u,0u};
      *(uint4*)&vv = z;
      if (tok < NTOK)
        vv.h = *(const f16x8*)&Vws[((size_t)(win*NTOK + tok))*256 + h*32 + seg*8];
      if (tok < 320){
#pragma unroll
        for (int k = 0; k < 8; ++k) Vt[(seg*8 + k)*328 + tok] = vv.s[k];
      }
    }
  }
  __syncthreads();

  // loop-invariant mask row (register-resident across all mt iters)
  float maddv[19];
#pragma unroll
  for (int nt = 0; nt < 19; ++nt) maddv[nt] = Madd[nt*16 + n16];

  u16* myP0 = &Pt[wave][0][0];
  u16* myP1 = &Pt[wave][1][0];
  int mt = wave;
  f16x8 qf = *(const f16x8*)&Qws[((size_t)(win*NTOK + mt*16 + n16))*256 + h*32 + q*8];

#pragma unroll 1
  for (; mt < 19; mt += 4){
    const int m0 = mt * 16;
    // per-(h,mt) f32 bias base for this lane: tile stride = 256 floats
    const float* bmt = Biasf + ((size_t)((h*19 + mt)*304 + n16))*16 + q*4;

    float S[19][4];
#pragma unroll
    for (int nt = 0; nt < 19; ++nt){
      f16x8 kf = *(const f16x8*)&Ks[(nt*16 + n16)*40 + q*8];
      f32x4 bv = *(const f32x4*)&bmt[nt*256];
      f32x4 c = { bv[0] + maddv[nt], bv[1] + maddv[nt],
                  bv[2] + maddv[nt], bv[3] + maddv[nt] };
      c = mfma16(qf, kf, c);
#pragma unroll
      for (int r = 0; r < 4; ++r) S[nt][r] = c[r];
    }

    // prefetch next iter's Q (hides L2 latency under softmax+PV)
    const int mtn = mt + 4;
    f16x8 qfn = qf;
    if (mtn < 19)
      qfn = *(const f16x8*)&Qws[((size_t)(win*NTOK + mtn*16 + n16))*256 + h*32 + q*8];

    // softmax per row (row = q*4+r in regs; cols across 16 lanes + 19 tiles)
    // exp2 domain: logits pre-scaled by log2e in prep -> single v_exp_f32.
    float rinv[4];
#pragma unroll
    for (int r = 0; r < 4; ++r){
      float a0 = fmaxf(fmaxf(S[0][r],  S[1][r]),  S[2][r]);
      float a1 = fmaxf(fmaxf(S[3][r],  S[4][r]),  S[5][r]);
      float a2 = fmaxf(fmaxf(S[6][r],  S[7][r]),  S[8][r]);
      float a3 = fmaxf(fmaxf(S[9][r],  S[10][r]), S[11][r]);
      float a4 = fmaxf(fmaxf(S[12][r], S[13][r]), S[14][r]);
      float a5 = fmaxf(fmaxf(S[15][r], S[16][r]), S[17][r]);
      float mx = fmaxf(fmaxf(fmaxf(a0, a1), fmaxf(a2, a3)),
                       fmaxf(fmaxf(a4, a5), S[18][r]));
      mx = fmaxf(mx, __shfl_xor(mx, 1));
      mx = fmaxf(mx, __shfl_xor(mx, 2));
      mx = fmaxf(mx, __shfl_xor(mx, 4));
      mx = fmaxf(mx, __shfl_xor(mx, 8));
      float s0 = 0.f, s1 = 0.f, s2 = 0.f, s3 = 0.f;
#pragma unroll
      for (int nt = 0; nt < 19; ++nt){
        float e = fexp2(S[nt][r] - mx);
        S[nt][r] = e;
        if ((nt & 3) == 0) s0 += e;
        else if ((nt & 3) == 1) s1 += e;
        else if ((nt & 3) == 2) s2 += e;
        else s3 += e;
      }
      float sum = (s0 + s1) + (s2 + s3);
      sum += __shfl_xor(sum, 1);
      sum += __shfl_xor(sum, 2);
      sum += __shfl_xor(sum, 4);
      sum += __shfl_xor(sum, 8);
      rinv[r] = 1.0f / sum;
    }

    // PV: per-tile pipeline, K=16 MFMA. Tile nt: P[16 rows][16 toks] goes
    // to the (nt&1) slot; write(nt+1) is issued before read(nt)'s MFMA.
    // Lane (q,n16): writes rows q*4+r at col n16; reads row n16, cols q*4+e
    // (b64); V b64 from Vt rows n16 / 16+n16. No lgkmcnt(0) drains needed:
    // per-wave DS is in-order (WAR safe), compiler emits counted waits (RAW).
    f32x4 o0 = {0.f,0.f,0.f,0.f}, o1 = {0.f,0.f,0.f,0.f};
#pragma unroll
    for (int r = 0; r < 4; ++r)
      myP0[(q*4 + r)*20 + n16] = f2h(S[0][r]);
#pragma unroll
    for (int nt = 0; nt < 19; ++nt){
      u16* cur = (nt & 1) ? myP1 : myP0;
      u16* nxt = (nt & 1) ? myP0 : myP1;
      if (nt < 18){
#pragma unroll
        for (int r = 0; r < 4; ++r)
          nxt[(q*4 + r)*20 + n16] = f2h(S[nt+1][r]);
      }
      f16x4 pa = *(const f16x4*)&cur[n16*20 + q*4];
      f16x4 v0 = *(const f16x4*)&Vt[n16*328        + nt*16 + q*4];
      f16x4 v1 = *(const f16x4*)&Vt[(16 + n16)*328 + nt*16 + q*4];
      o0 = mfma16k16(pa, v0, o0);
      o1 = mfma16k16(pa, v1, o1);
    }

#pragma unroll
    for (int r = 0; r < 4; ++r){
      int tok = m0 + q*4 + r;
      if (tok < NTOK){
        size_t base = ((size_t)(win*NTOK + tok))*256 + h*32;
        Ows[base + n16]      = f2h(o0[r] * rinv[r]);
        Ows[base + 16 + n16] = f2h(o1[r] * rinv[r]);
      }
    }
    qf = qfn;
  }
}

// out-proj GEMM: Ows(75264x256) @ WoutT -> scatter to (l,x,y,w1,w2,d)
// R3: same LDS-staged B + coalesced-C structure as qkv.
__global__ __launch_bounds__(256, 4) void dfab_proj2_kernel(
    const u16* __restrict__ Ows, const u16* __restrict__ wot,
    void* __restrict__ Outv, const int* __restrict__ flagp)
{
  __shared__ __align__(16) u16   Bs[2][4096];     // 16,384 B
  __shared__ __align__(16) float Csf[4][16 * 64]; // 16,384 B

  const int tid = threadIdx.x;
  const int wave = tid >> 6, lane = tid & 63;
  const int q = lane >> 4, n16 = lane & 15;
  const int mr = blockIdx.x * 64 + wave * 16;
  const int f32m = *(const volatile int*)flagp;

  stageB(wot, 0, &Bs[0][0], wave, lane);

  f16x8 afr[8];
#pragma unroll
  for (int ks = 0; ks < 8; ++ks)
    afr[ks] = *(const f16x8*)&Ows[((size_t)(mr + n16))*256 + ks*32 + q*8];

  // readback row bases (named scalars, rule #20)
  const int rbrow = lane >> 3, seg = lane & 7;
  size_t ob0, ob1;
  {
    int m = mr + rbrow;     int win = m / 294, tok = m - win*294;
    int l = tok / 49, rr = tok - l*49;
    ob0 = ((size_t)((l*256 + win)*49 + rr))*256;
    m = mr + 8 + rbrow;     win = m / 294; tok = m - win*294;
    l = tok / 49; rr = tok - l*49;
    ob1 = ((size_t)((l*256 + win)*49 + rr))*256;
  }

  float* myC = &Csf[wave][0];
  __syncthreads();                        // Bs[0] landed

#pragma unroll 1
  for (int g4 = 0; g4 < 4; ++g4){
#pragma unroll
    for (int t = 0; t < 4; ++t){
      const int nt = g4*4 + t;
      if (nt < 15) stageB(wot, nt+1, &Bs[(nt+1)&1][0], wave, lane);
      const u16* bb = &Bs[nt&1][0];
      f16x8 bfr[8];
#pragma unroll
      for (int ks = 0; ks < 8; ++ks) bfr[ks] = readB(bb, ks, q, n16);
      f32x4 c0 = {0.f,0.f,0.f,0.f}, c1 = {0.f,0.f,0.f,0.f};
#pragma unroll
      for (int ks = 0; ks < 4; ++ks){
        c0 = mfma16(afr[ks],     bfr[ks],     c0);
        c1 = mfma16(afr[ks + 4], bfr[ks + 4], c1);
      }
#pragma unroll
      for (int r = 0; r < 4; ++r)
        myC[(q*4 + r)*64 + t*16 + n16] = c0[r] + c1[r];
      __syncthreads();
    }
    __asm__ volatile("s_waitcnt lgkmcnt(0)" ::: "memory");
#pragma unroll
    for (int p = 0; p < 2; ++p){
      const int row = p*8 + rbrow;
      const size_t ob = p ? ob1 : ob0;
      f32x4 v0 = *(const f32x4*)&myC[row*64 + seg*8];
      f32x4 v1 = *(const f32x4*)&myC[row*64 + seg*8 + 4];
      if (f32m){
        *(f32x4*)&((float*)Outv)[ob + g4*64 + seg*8]     = v0;
        *(f32x4*)&((float*)Outv)[ob + g4*64 + seg*8 + 4] = v1;
      } else {
        union{ u32 w[4]; u16 h[8]; } pk;
        pk.h[0]=f2b(v0[0]); pk.h[1]=f2b(v0[1]); pk.h[2]=f2b(v0[2]); pk.h[3]=f2b(v0[3]);
        pk.h[4]=f2b(v1[0]); pk.h[5]=f2b(v1[1]); pk.h[6]=f2b(v1[2]); pk.h[7]=f2b(v1[3]);
        *(uint4*)&((u16*)Outv)[ob + g4*64 + seg*8] = *(const uint4*)&pk.w[0];
      }
    }
  }
}

// =========================================================================
// OLD PATH (proven-correct fallback if workspace is too small)
// =========================================================================
__global__ __launch_bounds__(256) void dfab_attn_kernel(
    const void* __restrict__ Xv, const int* __restrict__ Mask,
    const void* __restrict__ Wqkvv, const void* __restrict__ BiasTv,
    const int* __restrict__ RelIdx, u16* __restrict__ Obuf,
    const int* __restrict__ flagp)
{
  __shared__ __align__(16) char lds[59736];
  u16* Ks   = (u16*)(lds);
  u16* Vt   = (u16*)(lds + 19992);
  u16* Wp   = (u16*)(lds + 39192);
  u16* Xs   = (u16*)(lds + 47512);
  u16* Wqt  = (u16*)(lds + 39192);
  u32* Pb   = (u32*)(lds + 55832);
  float* Madd = (float*)(lds + 58264);
  u16* Qb   = (u16*)(lds + 59480);

  const int tid = threadIdx.x;
  const int bx  = blockIdx.x;
  const int win = bx >> 3, h = bx & 7;

  const int f32m = *(const volatile int*)flagp;
  const u16*   Xb = (const u16*)Xv;       const float* Xf = (const float*)Xv;
  const u16*   Wb = (const u16*)Wqkvv;    const float* Wf = (const float*)Wqkvv;
  const u16*   Bb = (const u16*)BiasTv;   const float* Bf = (const float*)BiasTv;

  for (int j = tid; j < 304; j += 256){
    float mv = -1e30f;
    if (j < NTOK){ int l = j / 49, r = j - l * 49;
      mv = (Mask[(win * 49 + r) * 6 + l] != 0) ? 0.0f : -1e30f; }
    Madd[j] = mv;
  }
  for (int idx = tid; idx < 32 * 6; idx += 256){
    int c = idx / 6; Vt[c * VT_STRIDE + NTOK + (idx - c * 6)] = 0;
  }

#pragma unroll 1
  for (int p = 0; p < 4; ++p){
    const int kind = p >> 1;
    const int colbase = 256 + kind * 256 + h * 32 + (p & 1) * 16;
    __syncthreads();
    for (int idx = tid; idx < 16 * 128; idx += 256){
      int c = idx & 15, d2 = idx >> 4;
      float w0, w1;
      if (f32m){ w0 = Wf[(2 * d2) * 768 + colbase + c]; w1 = Wf[(2 * d2 + 1) * 768 + colbase + c]; }
      else     { w0 = b2f(Wb[(2 * d2) * 768 + colbase + c]); w1 = b2f(Wb[(2 * d2 + 1) * 768 + colbase + c]); }
      *(u32*)&Wp[c * WST + 2 * d2] = pack2h(w0, w1);
    }
#pragma unroll 1
    for (int jt = 0; jt < 19; ++jt){
      const int j0 = jt * 16;
      const int nj = (NTOK - j0 < 16) ? (NTOK - j0) : 16;
      __syncthreads();
      for (int idx = tid; idx < nj * 128; idx += 256){
        int jl = idx >> 7, d2 = idx & 127;
        int tok = j0 + jl; int l = tok / 49, r = tok - l * 49;
        size_t off = (size_t)((l * 256 + win) * 49 + r) * 256 + 2 * d2;
        u32 hp;
        if (f32m){ float2 xx = *(const float2*)&Xf[off]; hp = pack2h(xx.x, xx.y); }
        else     { hp = bfp2h(*(const u32*)&Xb[off]); }
        *(u32*)&Xs[jl * WST + 2 * d2] = hp;
      }
      __syncthreads();
      const int jl = tid >> 4, c = tid & 15;
      const u32* xp = (const u32*)&Xs[jl * WST];
      const u32* wp = (const u32*)&Wp[c * WST];
      float a0 = 0.f, a1 = 0.f;
#pragma unroll 4
      for (int d2 = 0; d2 < 128; d2 += 4){
        uint2 xa = *(const uint2*)(xp + d2), xb = *(const uint2*)(xp + d2 + 2);
        uint2 wa = *(const uint2*)(wp + d2), wb = *(const uint2*)(wp + d2 + 2);
        a0 = dot2f(xa.x, wa.x, a0); a1 = dot2f(xa.y, wa.y, a1);
        a0 = dot2f(xb.x, wb.x, a0); a1 = dot2f(xb.y, wb.y, a1);
      }
      if (jl < nj){
        u16 hv = f2h(a0 + a1);
        int tok = j0 + jl;
        if (kind == 0) Ks[tok * KS_STRIDE + (p & 1) * 16 + c] = hv;
        else           Vt[((p & 1) * 16 + c) * VT_STRIDE + tok] = hv;
      }
    }
  }
  __syncthreads();
  for (int idx = tid; idx < 32 * 128; idx += 256){
    int c = idx & 31, d2 = idx >> 5;
    float w0, w1;
    if (f32m){ w0 = Wf[(2 * d2) * 768 + h * 32 + c]; w1 = Wf[(2 * d2 + 1) * 768 + h * 32 + c]; }
    else     { w0 = b2f(Wb[(2 * d2) * 768 + h * 32 + c]); w1 = b2f(Wb[(2 * d2 + 1) * 768 + h * 32 + c]); }
    *(u32*)&Wqt[c * WST + 2 * d2] = pack2h(w0, w1);
  }
  __syncthreads();

  const int wave = tid >> 6, lane = tid & 63;
  const int hf = lane >> 5, c32 = lane & 31;
  u32* mypb = Pb + wave * 152;
  u16* qbw  = Qb + wave * 32;

  for (int i = wave; i < NTOK; i += 4){
    const int li = i / 49, ri = i - li * 49;
    const size_t rowoff = (size_t)((li * 256 + win) * 49 + ri) * 256;
    const u32* wqp = (const u32*)&Wqt[c32 * WST];
    float q0 = 0.f, q1 = 0.f;
    if (f32m){
      const float4* xr4 = (const float4*)&Xf[rowoff];
#pragma unroll 4
      for (int d2 = hf * 64; d2 < hf * 64 + 64; d2 += 2){
        uint2 wq = *(const uint2*)(wqp + d2);
        float4 xx = xr4[d2 >> 1];
        q0 = dot2f(pack2h(xx.x, xx.y), wq.x, q0);
        q1 = dot2f(pack2h(xx.z, xx.w), wq.y, q1);
      }
    } else {
      const u32* xr = (const u32*)&Xb[rowoff];
#pragma unroll 4
      for (int d2 = hf * 64; d2 < hf * 64 + 64; d2 += 2){
        uint2 wq = *(const uint2*)(wqp + d2);
        q0 = dot2f(bfp2h(xr[d2]),     wq.x, q0);
        q1 = dot2f(bfp2h(xr[d2 + 1]), wq.y, q1);
      }
    }
    float qa = q0 + q1;
    qa += __shfl_xor(qa, 32);
    if (hf == 0) qbw[c32] = f2h(qa * 0.17677669529663687f);
    __asm__ volatile("s_waitcnt lgkmcnt(0)" ::: "memory");
    u32 qp[16];
#pragma unroll
    for (int cc = 0; cc < 16; ++cc) qp[cc] = *(const u32*)&qbw[2 * cc];

    float sv[5];
#pragma unroll
    for (int it = 0; it < 5; ++it){
      int j = it * 64 + lane;
      float a;
      if (j < NTOK){
        int nb = RelIdx[i * NTOK + j] * 8 + h;
        float bias = f32m ? Bf[nb] : b2f(Bb[nb]);
        float a0 = bias + Madd[j];
        float a1 = 0.f;
        const u16* kr = &Ks[j * KS_STRIDE];
#pragma unroll
        for (int cc = 0; cc < 16; cc += 2){
          a0 = dot2f(qp[cc],     *(const u32*)&kr[2 * cc],     a0);
          a1 = dot2f(qp[cc + 1], *(const u32*)&kr[2 * cc + 2], a1);
        }
        a = a0 + a1;
      } else a = -3e38f;
      sv[it] = a;
    }
    float m = sv[0];
#pragma unroll
    for (int it = 1; it < 5; ++it) m = fmaxf(m, sv[it]);
    for (int off = 32; off > 0; off >>= 1) m = fmaxf(m, __shfl_xor(m, off));
    float lsum = 0.f;
#pragma unroll
    for (int it = 0; it < 5; ++it){ float e = __expf(sv[it] - m); sv[it] = e; lsum += e; }
    for (int off = 32; off > 0; off >>= 1) lsum += __shfl_xor(lsum, off);
    const float rinv = 1.0f / lsum;
#pragma unroll
    for (int it = 0; it < 5; ++it){
      float pn = sv[it] * rinv;
      float po = __shfl_xor(pn, 1);
      int j = it * 64 + lane;
      if (!(lane & 1) && j < 304) mypb[j >> 1] = pack2h(pn, po);
    }
    __asm__ volatile("s_waitcnt lgkmcnt(0)" ::: "memory");
    const u16* vr = &Vt[c32 * VT_STRIDE];
    const int jb = hf * 148;
    float o0 = 0.f, o1 = 0.f;
#pragma unroll 4
    for (int g = 0; g < 37; ++g){
      int j = jb + 4 * g;
      uint2 vv = *(const uint2*)&vr[j];
      uint2 pp = *(const uint2*)&mypb[j >> 1];
      o0 = dot2f(pp.x, vv.x, o0);
      o1 = dot2f(pp.y, vv.y, o1);
    }
    float o = o0 + o1;
    o += __shfl_xor(o, 32);
    if (hf == 0)
      Obuf[(size_t)(win * NTOK + i) * 256 + h * 32 + c32] = f2b(o);
  }
}

__global__ __launch_bounds__(256) void dfab_proj_kernel(
    const u16* __restrict__ Obuf, const void* __restrict__ Woutv,
    void* __restrict__ Outv, const int* __restrict__ flagp)
{
  __shared__ __align__(16) char lds[33920];
  u16* Ot = (u16*)(lds);
  u16* Wt = (u16*)(lds + 16512);

  const int tid = threadIdx.x;
  const int bx = blockIdx.x;
  const int win = bx / 10, tile = bx - win * 10;
  const int t0 = tile * 32;
  const int nt = (NTOK - t0 < 32) ? (NTOK - t0) : 32;

  const int f32m = *(const volatile int*)flagp;
  const u16* Wob = (const u16*)Woutv; const float* Wof = (const float*)Woutv;

  for (int idx = tid; idx < nt * 128; idx += 256){
    int t = idx >> 7, k2 = idx & 127;
    u32 oo = *(const u32*)&Obuf[(size_t)(win * NTOK + t0 + t) * 256 + 2 * k2];
    *(u32*)&Ot[t * 258 + 2 * k2] = bfp2h(oo);
  }

  float acc[32];
#pragma unroll
  for (int t = 0; t < 32; ++t) acc[t] = 0.f;
  const int dd = tid;

#pragma unroll 1
  for (int kt = 0; kt < 8; ++kt){
    __syncthreads();
    for (int idx = tid; idx < 4096; idx += 256){
      int d = idx & 255, kk2 = idx >> 8;
      int k = kt * 32 + 2 * kk2;
      float w0, w1;
      if (f32m){ w0 = Wof[k * 256 + d]; w1 = Wof[(k + 1) * 256 + d]; }
      else     { w0 = b2f(Wob[k * 256 + d]); w1 = b2f(Wob[(k + 1) * 256 + d]); }
      *(u32*)&Wt[d * 34 + 2 * kk2] = pack2h(w0, w1);
    }
    __syncthreads();
#pragma unroll 2
    for (int kk2 = 0; kk2 < 16; ++kk2){
      u32 wp = *(const u32*)&Wt[dd * 34 + 2 * kk2];
      const u16* orow = &Ot[kt * 32 + 2 * kk2];
#pragma unroll 8
      for (int t = 0; t < 32; ++t){
        u32 op = *(const u32*)&orow[t * 258];
        acc[t] = dot2f(op, wp, acc[t]);
      }
    }
  }

  for (int t = 0; t < nt; ++t){
    int tok = t0 + t; int l = tok / 49, r = tok - l * 49;
    size_t oidx = (size_t)((l * 256 + win) * 49 + r) * 256 + dd;
    if (f32m) ((float*)Outv)[oidx] = acc[t];
    else      ((u16*)Outv)[oidx]   = f2b(acc[t]);
  }
}

// -------------------------------------------------------------------------
extern "C" void kernel_launch(void* const* d_in, const int* in_sizes, int n_in,
                              void* d_out, int out_size, void* d_ws, size_t ws_size,
                              hipStream_t stream) {
  (void)in_sizes; (void)n_in; (void)out_size;
  const void* x          = d_in[0];
  const int*  mask       = (const int*)d_in[1];
  const void* w_qkv      = d_in[2];
  const void* w_out      = d_in[3];
  const void* bias_table = d_in[4];
  const int*  rel_index  = (const int*)d_in[5];
  char* ws = (char*)d_ws;

  if (ws_size >= NEED_WS){
    // MFMA path
    u16* qws   = (u16*)(ws + QWS_OFF);
    u16* kws   = (u16*)(ws + KWS_OFF);
    u16* vws   = (u16*)(ws + VWS_OFF);
    u16* ows   = (u16*)(ws + OWS_OFF);
    float* bsf = (float*)(ws + BIASF_OFF);
    u16* wqt   = (u16*)(ws + WQT_OFF);
    u16* wot   = (u16*)(ws + WOT_OFF);
    int* flag  = (int*)(ws + FLAG2_OFF);
    dfab_probe_kernel<<<1, 64, 0, stream>>>((const u16*)x, flag);
    dfab_prep_kernel<<<3912, 256, 0, stream>>>(w_qkv, w_out, bias_table, rel_index,
                                               wqt, wot, bsf, flag);
    dfab_qkv_kernel<<<1176, 256, 0, stream>>>(x, wqt, qws, kws, vws, flag);
    dfab_attn2_kernel<<<2048, 256, 0, stream>>>(qws, kws, vws, bsf, mask, ows);
    dfab_proj2_kernel<<<1176, 256, 0, stream>>>(ows, wot, d_out, flag);
  } else {
    // fallback: proven dot2 path
    u16* obuf = (u16*)ws;
    int* flag = (int*)(ws + FLAG_OFF);
    dfab_probe_kernel<<<1, 64, 0, stream>>>((const u16*)x, flag);
    dfab_attn_kernel<<<2048, 256, 0, stream>>>(x, mask, w_qkv, bias_table, rel_index, obuf, flag);
    dfab_proj_kernel<<<2560, 256, 0, stream>>>(obuf, w_out, d_out, flag);
  }
}

// Round 9
// 363.068 us; speedup vs baseline: 1.2145x; 1.2145x over previous
//
#include <hip/hip_runtime.h>

typedef unsigned short u16;
typedef unsigned int   u32;

#define NTOK 294
#define KS_STRIDE 34
#define VT_STRIDE 300
#define WST 260
#define OBUF_BYTES 38535168ull   // old path: 256*294*256 u16
#define FLAG_OFF (OBUF_BYTES)    // old path flag location (proven to fit)

// ---- new-path workspace layout (bytes) ----
#define ROWS_ALLOC 75280ull                      // 75264 rows + 16 slack
#define BUFB (ROWS_ALLOC * 512ull)               // 38,543,360 per f16 [rows][256] buffer
#define QWS_OFF   0ull
#define KWS_OFF   (QWS_OFF + BUFB)
#define VWS_OFF   (KWS_OFF + BUFB)
#define OWS_OFF   (VWS_OFF + BUFB)
#define BIASF_OFF (OWS_OFF + BUFB)               // f32 [8][19][304][16] = 2,957,312
#define BIASF_BYTES 2957312ull
#define WQT_OFF   (BIASF_OFF + BIASF_BYTES)      // 768*256 f16  = 393,216
#define WOT_OFF   (WQT_OFF + 393216ull)          // 256*256 f16  = 131,072
#define FLAG2_OFF (WOT_OFF + 131072ull)
#define NEED_WS   (FLAG2_OFF + 4ull)             // ~157.7 MB

typedef __fp16 hv2  __attribute__((ext_vector_type(2)));
typedef __fp16 f16x4 __attribute__((ext_vector_type(4)));
typedef __fp16 f16x8 __attribute__((ext_vector_type(8)));
typedef float  f32x4 __attribute__((ext_vector_type(4)));

__device__ __forceinline__ float b2f(u16 v){ union{u32 u; float f;} x; x.u = ((u32)v) << 16; return x.f; }
__device__ __forceinline__ u16 f2b(float f){
  union{float f; u32 u;} x; x.f = f; u32 u = x.u;
  return (u16)((u + 0x7fffu + ((u >> 16) & 1u)) >> 16);      // RTNE bf16
}
__device__ __forceinline__ u32 pack2h(float a, float b){
#if __has_builtin(__builtin_amdgcn_cvt_pkrtz)
  auto r = __builtin_amdgcn_cvt_pkrtz(a, b);
  union{ decltype(r) h; u32 u; } x; x.h = r; return x.u;
#else
  union{ hv2 h; u32 u; } x; x.h[0] = (__fp16)a; x.h[1] = (__fp16)b; return x.u;
#endif
}
__device__ __forceinline__ u32 bfp2h(u32 bfp){
  union{u32 u; float f;} lo, hi; lo.u = bfp << 16; hi.u = bfp & 0xffff0000u;
  return pack2h(lo.f, hi.f);
}
__device__ __forceinline__ u16 f2h(float a){ return (u16)(pack2h(a, 0.0f) & 0xffffu); }

__device__ __forceinline__ float dot2f(u32 a, u32 b, float c){
#if __has_builtin(__builtin_amdgcn_fdot2)
  union{u32 u; hv2 h;} A, B; A.u = a; B.u = b;
  return __builtin_amdgcn_fdot2(A.h, B.h, c, false);
#else
  union{u32 u; __fp16 h[2];} A, B; A.u = a; B.u = b;
  return c + (float)A.h[0]*(float)B.h[0] + (float)A.h[1]*(float)B.h[1];
#endif
}

// raw HW 2^x (single v_exp_f32). Logits are pre-scaled by log2e in prep,
// so softmax in the exp2 domain is mathematically identical.
__device__ __forceinline__ float fexp2(float x){
#if __has_builtin(__builtin_amdgcn_exp2f)
  return __builtin_amdgcn_exp2f(x);
#else
  return exp2f(x);
#endif
}

__device__ __forceinline__ f32x4 mfma16(f16x8 a, f16x8 b, f32x4 c){
  return __builtin_amdgcn_mfma_f32_16x16x32_f16(a, b, c, 0, 0, 0);
}
// K=16 variant: A,B = 4 f16 (2 VGPR). Lane (q,n16): A row=n16 k=q*4+e;
// B col=n16 k=q*4+e; C/D same as 16x16x32 (col=lane&15, row=q*4+reg).
__device__ __forceinline__ f32x4 mfma16k16(f16x4 a, f16x4 b, f32x4 c){
  return __builtin_amdgcn_mfma_f32_16x16x16f16(a, b, c, 0, 0, 0);
}

// async global->LDS, 16B per lane. LDS dest is wave-uniform base + lane*16
// (m104) -> dest must be linear; swizzling is done on the GLOBAL source
// addresses + the LDS read side (T21: both-sides-or-neither).
__device__ __forceinline__ void gl2lds16(const void* g, void* l){
#if __has_builtin(__builtin_amdgcn_global_load_lds)
  __builtin_amdgcn_global_load_lds(
      (const __attribute__((address_space(1))) void*)g,
      (__attribute__((address_space(3))) void*)l, 16, 0, 0);
#else
  *(f16x8*)l = *(const f16x8*)g;
#endif
}

// Stage one 16x256-f16 B tile (8 KB) into LDS, double-buffer slot `buf`.
// Source granules pre-swizzled with g ^= (row&7) so the swizzled ds_read
// (bank-conflict-free for the (n16,q) fragment pattern) sees correct data.
__device__ __forceinline__ void stageB(const u16* __restrict__ wsrc, int nt,
                                       u16* lbase, int wave, int lane){
#pragma unroll
  for (int c = 0; c < 2; ++c){
    int G   = (c*4 + wave)*64 + lane;           // granule 0..511 (16B units)
    int row = G >> 5, g = G & 31;
    int sg  = g ^ (row & 7);
    const u16* src = wsrc + (size_t)nt*4096 + row*256 + sg*8;
    u16* dst = lbase + (size_t)(c*4 + wave)*512;
    gl2lds16(src, dst);
  }
}

// swizzled B fragment read: B[n16][ks*32+q*8] lives at granule (ks*4+q)^(n16&7)
__device__ __forceinline__ f16x8 readB(const u16* bb, int ks, int q, int n16){
  return *(const f16x8*)&bb[n16*256 + (((ks*4 + q) ^ (n16 & 7)) * 8)];
}

// -------------------------------------------------------------------------
// Probe: bf16 (flag 0) vs f32 (flag 1) input dtype, from exponent stats.
// -------------------------------------------------------------------------
__global__ void dfab_probe_kernel(const u16* __restrict__ X, int* __restrict__ flag)
{
  const int lane = threadIdx.x;   // 64 threads
  int cnt = 0;
#pragma unroll
  for (int k = 0; k < 8; ++k){
    u16 v = X[lane * 8 + k];
    int e = (v >> 7) & 0xFF;
    cnt += (e < 96 || e > 158) ? 1 : 0;
  }
  for (int off = 32; off > 0; off >>= 1) cnt += __shfl_xor(cnt, off);
  if (lane == 0) *flag = (cnt > 64) ? 1 : 0;
}

// =========================================================================
// NEW PATH
// =========================================================================

// prep: WqkvT[n][k] f16 (Q-scaled), WoutT[n][k] f16,
// Biasf f32 [h][mt][col][16rows] (log2e-folded, R7 tiled layout: attn2's
// per-m-tile bias init becomes one dwordx4 + 4 adds per tile).
__global__ __launch_bounds__(256) void dfab_prep_kernel(
    const void* __restrict__ Wqkvv, const void* __restrict__ Woutv,
    const void* __restrict__ BiasTv, const int* __restrict__ RelIdx,
    u16* __restrict__ wqt, u16* __restrict__ wot, float* __restrict__ biasf,
    const int* __restrict__ flagp)
{
  const int f32m = *(const volatile int*)flagp;
  const u16* Wb = (const u16*)Wqkvv;  const float* Wf = (const float*)Wqkvv;
  const u16* Ob = (const u16*)Woutv;  const float* Of = (const float*)Woutv;
  const u16* Bb = (const u16*)BiasTv; const float* Bf = (const float*)BiasTv;
  int idx = blockIdx.x * 256 + threadIdx.x;          // grid 3912 -> 1,001,472
  if (idx < 196608){
    int n = idx >> 8, k = idx & 255;
    float w = f32m ? Wf[k*768 + n] : b2f(Wb[k*768 + n]);
    if (n < 256) w *= 0.25503487f;                   // dh^-0.5 * log2(e)
    wqt[n*256 + k] = f2h(w);
  } else if (idx < 262144){
    int t = idx - 196608; int n = t >> 8, k = t & 255;
    float w = f32m ? Of[k*256 + n] : b2f(Ob[k*256 + n]);
    wot[n*256 + k] = f2h(w);
  } else {
    int t = idx - 262144;                            // 739,328 = 8*19*304*16
    int hh = t / 92416; int rem = t - hh * 92416;    // 92416 = 19*304*16
    int mt = rem / 4864; int r2 = rem - mt * 4864;   // 4864 = 304*16
    int col = r2 >> 4;  int rw = r2 & 15;
    int i = mt * 16 + rw;                            // row (query token)
    float v = 0.f;
    if (i < NTOK && col < NTOK){
      int nb = RelIdx[i * NTOK + col] * 8 + hh;
      v = (f32m ? Bf[nb] : b2f(Bb[nb])) * 1.4426950409f;   // log2(e)
    }
    biasf[((size_t)((hh*19 + mt)*304 + col))*16 + rw] = v;
  }
}

// QKV GEMM: rows m = win*294+tok (M=75264), K=256, N=768 -> Q/K/V f16 ws
// R3 restructure (confirmed: qkv left top-5, total 626->416): LDS-staged B
// via global_load_lds (dbuf, shared by 4 waves), swizzled ds_read_b128
// fragments, C coalesced through per-wave LDS tile into dwordx4 stores.
__global__ __launch_bounds__(256, 4) void dfab_qkv_kernel(
    const void* __restrict__ Xv, const u16* __restrict__ wqt,
    u16* __restrict__ Qws, u16* __restrict__ Kws, u16* __restrict__ Vws,
    const int* __restrict__ flagp)
{
  __shared__ __align__(16) union {
    u16 xs[64 * 264];                        // 33,792 B (staging phase)
    struct { u16 bs[2][4096]; u16 cs[4][1024]; } p;  // 16K + 8K (loop phase)
  } sm;

  const int tid = threadIdx.x;
  const int m0 = blockIdx.x * 64;
  const int f32m = *(const volatile int*)flagp;
  const u16* Xb = (const u16*)Xv; const float* Xf = (const float*)Xv;
  const int wave = tid >> 6, lane = tid & 63;
  const int q = lane >> 4, n16 = lane & 15;

  // ---- phase 1: stage X rows into xs, load A fragments ----
  for (int idx = tid; idx < 64 * 128; idx += 256){
    int rl = idx >> 7, d2 = idx & 127;
    int m = m0 + rl; int win = m / 294, tok = m - win * 294;
    int l = tok / 49, r = tok - l * 49;
    size_t src = ((size_t)((l*256 + win)*49 + r))*256 + 2*d2;
    u32 hp;
    if (f32m){ float2 xx = *(const float2*)&Xf[src]; hp = pack2h(xx.x, xx.y); }
    else     { hp = bfp2h(*(const u32*)&Xb[src]); }
    *(u32*)&sm.xs[rl * 264 + 2*d2] = hp;
  }
  __syncthreads();

  f16x8 afr[8];
#pragma unroll
  for (int ks = 0; ks < 8; ++ks)
    afr[ks] = *(const f16x8*)&sm.xs[(wave*16 + n16) * 264 + ks*32 + q*8];
  __syncthreads();                       // all afr reads done before xs is overwritten

  // ---- phase 2: B-tile loop (bs/cs overlay xs) ----
  stageB(wqt, 0, &sm.p.bs[0][0], wave, lane);
  __syncthreads();                       // bs[0] landed (barrier drains vmcnt)

  u16* myC = &sm.p.cs[wave][0];
  const size_t rowb = (size_t)(m0 + wave*16);
  const int rbrow = lane >> 3, seg = lane & 7;

#pragma unroll 1
  for (int grp = 0; grp < 12; ++grp){
    u16* dstp = (grp < 4) ? Qws : ((grp < 8) ? Kws : Vws);
    const int g4 = grp & 3;
#pragma unroll
    for (int t = 0; t < 4; ++t){
      const int nt = grp*4 + t;
      if (nt < 47) stageB(wqt, nt+1, &sm.p.bs[(nt+1)&1][0], wave, lane);
      const u16* bb = &sm.p.bs[nt&1][0];
      f16x8 bfr[8];
#pragma unroll
      for (int ks = 0; ks < 8; ++ks) bfr[ks] = readB(bb, ks, q, n16);
      f32x4 c0 = {0.f,0.f,0.f,0.f}, c1 = {0.f,0.f,0.f,0.f};
#pragma unroll
      for (int ks = 0; ks < 4; ++ks){
        c0 = mfma16(afr[ks],     bfr[ks],     c0);
        c1 = mfma16(afr[ks + 4], bfr[ks + 4], c1);
      }
#pragma unroll
      for (int r = 0; r < 4; ++r)
        myC[(q*4 + r)*64 + t*16 + n16] = f2h(c0[r] + c1[r]);
      __syncthreads();                   // bs[(nt+1)&1] landed; cs writes drained
    }
    // wide coalesced C store: 16 rows x 128 B per wave, dwordx4 per lane
    __asm__ volatile("s_waitcnt lgkmcnt(0)" ::: "memory");
#pragma unroll
    for (int p = 0; p < 2; ++p){
      const int row = p*8 + rbrow;
      f16x8 v = *(const f16x8*)&myC[row*64 + seg*8];
      *(f16x8*)&dstp[(rowb + row)*256 + g4*64 + seg*8] = v;
    }
  }
}

// Attention: block=(win,head); waves own independent 16-row m-tiles.
// R1 (rule #20): all S indices compile-time -> S in VGPRs.
// R4 (confirmed): K in LDS Ks[304x40], V^T in Vt, wide staging loads.
// R5 FAILED: kf in regs -> rematerialized. Only LDS staging pins placement.
// R6: exp2-domain softmax (kept).
// R7 SPILLED: __launch_bounds__(256,3) capped VGPR at 84 -> S spilled
// (WRITE_SIZE 37.6->123.6 MB, dur 213us). The PV pipeline / LDS diet / f32
// bias were confounded, not refuted.
// R8: single-variable revert to (256,2) (VGPR cap 256 -> no spill). LDS
// 51.7KB still allows 3 blocks/CU if the RA lands <=170 VGPRs - the diet's
// payoff without the bound that sabotaged it.
__global__ __launch_bounds__(256, 2) void dfab_attn2_kernel(
    const u16* __restrict__ Qws, const u16* __restrict__ Kws,
    const u16* __restrict__ Vws, const float* __restrict__ Biasf,
    const int* __restrict__ Mask, u16* __restrict__ Ows)
{
  __shared__ __align__(16) u16 Ks[304 * 40];         // 24,320 B (stride 40 u16 = 80 B)
  __shared__ __align__(16) u16 Vt[32 * 328];         // 20,992 B (stride 328)
  __shared__ __align__(16) u16 Pt[4][2][16 * 20];    // 5,120 B (2-slot dbuf per wave)
  __shared__ float Madd[304];

  const int tid = threadIdx.x;
  const int win = blockIdx.x >> 3, h = blockIdx.x & 7;
  const int wave = tid >> 6, lane = tid & 63;
  const int q = lane >> 4, n16 = lane & 15;

  for (int j = tid; j < 304; j += 256){
    float mv = -1e30f;
    if (j < NTOK){ int l = j / 49, r = j - l * 49;
      mv = (Mask[(win * 49 + r) * 6 + l] != 0) ? 0.0f : -1e30f; }
    Madd[j] = mv;
  }

  // stage K -> Ks[row][32] (16B per (row,seg)); zero pad rows 294..303.
  {
    const int rr0 = tid >> 2, seg = tid & 3;
#pragma unroll
    for (int p = 0; p < 5; ++p){
      int rr = rr0 + p*64;
      if (rr < NTOK){
        f16x8 kv = *(const f16x8*)&Kws[((size_t)(win*NTOK + rr))*256 + h*32 + seg*8];
        *(f16x8*)&Ks[rr*40 + seg*8] = kv;
      }
    }
    if (tid < 40){
      int rr = NTOK + (tid >> 2);
      uint4 z = {0u,0u,0u,0u};
      *(uint4*)&Ks[rr*40 + seg*8] = z;
    }
    // stage V -> Vt[c][tok] transpose, 16B vector loads (tok<320 zero-fill)
#pragma unroll
    for (int p = 0; p < 5; ++p){
      int tok = rr0 + p*64;                          // 0..319
      union{ f16x8 h; u16 s[8]; } vv;
      uint4 z = {0u,0u,0u,0u};
      *(uint4*)&vv = z;
      if (tok < NTOK)
        vv.h = *(const f16x8*)&Vws[((size_t)(win*NTOK + tok))*256 + h*32 + seg*8];
      if (tok < 320){
#pragma unroll
        for (int k = 0; k < 8; ++k) Vt[(seg*8 + k)*328 + tok] = vv.s[k];
      }
    }
  }
  __syncthreads();

  // loop-invariant mask row (register-resident across all mt iters)
  float maddv[19];
#pragma unroll
  for (int nt = 0; nt < 19; ++nt) maddv[nt] = Madd[nt*16 + n16];

  u16* myP0 = &Pt[wave][0][0];
  u16* myP1 = &Pt[wave][1][0];
  int mt = wave;
  f16x8 qf = *(const f16x8*)&Qws[((size_t)(win*NTOK + mt*16 + n16))*256 + h*32 + q*8];

#pragma unroll 1
  for (; mt < 19; mt += 4){
    const int m0 = mt * 16;
    // per-(h,mt) f32 bias base for this lane: tile stride = 256 floats
    const float* bmt = Biasf + ((size_t)((h*19 + mt)*304 + n16))*16 + q*4;

    float S[19][4];
#pragma unroll
    for (int nt = 0; nt < 19; ++nt){
      f16x8 kf = *(const f16x8*)&Ks[(nt*16 + n16)*40 + q*8];
      f32x4 bv = *(const f32x4*)&bmt[nt*256];
      f32x4 c = { bv[0] + maddv[nt], bv[1] + maddv[nt],
                  bv[2] + maddv[nt], bv[3] + maddv[nt] };
      c = mfma16(qf, kf, c);
#pragma unroll
      for (int r = 0; r < 4; ++r) S[nt][r] = c[r];
    }

    // prefetch next iter's Q (hides L2 latency under softmax+PV)
    const int mtn = mt + 4;
    f16x8 qfn = qf;
    if (mtn < 19)
      qfn = *(const f16x8*)&Qws[((size_t)(win*NTOK + mtn*16 + n16))*256 + h*32 + q*8];

    // softmax per row (row = q*4+r in regs; cols across 16 lanes + 19 tiles)
    // exp2 domain: logits pre-scaled by log2e in prep -> single v_exp_f32.
    float rinv[4];
#pragma unroll
    for (int r = 0; r < 4; ++r){
      float a0 = fmaxf(fmaxf(S[0][r],  S[1][r]),  S[2][r]);
      float a1 = fmaxf(fmaxf(S[3][r],  S[4][r]),  S[5][r]);
      float a2 = fmaxf(fmaxf(S[6][r],  S[7][r]),  S[8][r]);
      float a3 = fmaxf(fmaxf(S[9][r],  S[10][r]), S[11][r]);
      float a4 = fmaxf(fmaxf(S[12][r], S[13][r]), S[14][r]);
      float a5 = fmaxf(fmaxf(S[15][r], S[16][r]), S[17][r]);
      float mx = fmaxf(fmaxf(fmaxf(a0, a1), fmaxf(a2, a3)),
                       fmaxf(fmaxf(a4, a5), S[18][r]));
      mx = fmaxf(mx, __shfl_xor(mx, 1));
      mx = fmaxf(mx, __shfl_xor(mx, 2));
      mx = fmaxf(mx, __shfl_xor(mx, 4));
      mx = fmaxf(mx, __shfl_xor(mx, 8));
      float s0 = 0.f, s1 = 0.f, s2 = 0.f, s3 = 0.f;
#pragma unroll
      for (int nt = 0; nt < 19; ++nt){
        float e = fexp2(S[nt][r] - mx);
        S[nt][r] = e;
        if ((nt & 3) == 0) s0 += e;
        else if ((nt & 3) == 1) s1 += e;
        else if ((nt & 3) == 2) s2 += e;
        else s3 += e;
      }
      float sum = (s0 + s1) + (s2 + s3);
      sum += __shfl_xor(sum, 1);
      sum += __shfl_xor(sum, 2);
      sum += __shfl_xor(sum, 4);
      sum += __shfl_xor(sum, 8);
      rinv[r] = 1.0f / sum;
    }

    // PV: per-tile pipeline, K=16 MFMA. Tile nt: P[16 rows][16 toks] goes
    // to the (nt&1) slot; write(nt+1) is issued before read(nt)'s MFMA.
    // Lane (q,n16): writes rows q*4+r at col n16; reads row n16, cols q*4+e
    // (b64); V b64 from Vt rows n16 / 16+n16. No lgkmcnt(0) drains needed:
    // per-wave DS is in-order (WAR safe), compiler emits counted waits (RAW).
    f32x4 o0 = {0.f,0.f,0.f,0.f}, o1 = {0.f,0.f,0.f,0.f};
#pragma unroll
    for (int r = 0; r < 4; ++r)
      myP0[(q*4 + r)*20 + n16] = f2h(S[0][r]);
#pragma unroll
    for (int nt = 0; nt < 19; ++nt){
      u16* cur = (nt & 1) ? myP1 : myP0;
      u16* nxt = (nt & 1) ? myP0 : myP1;
      if (nt < 18){
#pragma unroll
        for (int r = 0; r < 4; ++r)
          nxt[(q*4 + r)*20 + n16] = f2h(S[nt+1][r]);
      }
      f16x4 pa = *(const f16x4*)&cur[n16*20 + q*4];
      f16x4 v0 = *(const f16x4*)&Vt[n16*328        + nt*16 + q*4];
      f16x4 v1 = *(const f16x4*)&Vt[(16 + n16)*328 + nt*16 + q*4];
      o0 = mfma16k16(pa, v0, o0);
      o1 = mfma16k16(pa, v1, o1);
    }

#pragma unroll
    for (int r = 0; r < 4; ++r){
      int tok = m0 + q*4 + r;
      if (tok < NTOK){
        size_t base = ((size_t)(win*NTOK + tok))*256 + h*32;
        Ows[base + n16]      = f2h(o0[r] * rinv[r]);
        Ows[base + 16 + n16] = f2h(o1[r] * rinv[r]);
      }
    }
    qf = qfn;
  }
}

// out-proj GEMM: Ows(75264x256) @ WoutT -> scatter to (l,x,y,w1,w2,d)
// R3: same LDS-staged B + coalesced-C structure as qkv.
__global__ __launch_bounds__(256, 4) void dfab_proj2_kernel(
    const u16* __restrict__ Ows, const u16* __restrict__ wot,
    void* __restrict__ Outv, const int* __restrict__ flagp)
{
  __shared__ __align__(16) u16   Bs[2][4096];     // 16,384 B
  __shared__ __align__(16) float Csf[4][16 * 64]; // 16,384 B

  const int tid = threadIdx.x;
  const int wave = tid >> 6, lane = tid & 63;
  const int q = lane >> 4, n16 = lane & 15;
  const int mr = blockIdx.x * 64 + wave * 16;
  const int f32m = *(const volatile int*)flagp;

  stageB(wot, 0, &Bs[0][0], wave, lane);

  f16x8 afr[8];
#pragma unroll
  for (int ks = 0; ks < 8; ++ks)
    afr[ks] = *(const f16x8*)&Ows[((size_t)(mr + n16))*256 + ks*32 + q*8];

  // readback row bases (named scalars, rule #20)
  const int rbrow = lane >> 3, seg = lane & 7;
  size_t ob0, ob1;
  {
    int m = mr + rbrow;     int win = m / 294, tok = m - win*294;
    int l = tok / 49, rr = tok - l*49;
    ob0 = ((size_t)((l*256 + win)*49 + rr))*256;
    m = mr + 8 + rbrow;     win = m / 294; tok = m - win*294;
    l = tok / 49; rr = tok - l*49;
    ob1 = ((size_t)((l*256 + win)*49 + rr))*256;
  }

  float* myC = &Csf[wave][0];
  __syncthreads();                        // Bs[0] landed

#pragma unroll 1
  for (int g4 = 0; g4 < 4; ++g4){
#pragma unroll
    for (int t = 0; t < 4; ++t){
      const int nt = g4*4 + t;
      if (nt < 15) stageB(wot, nt+1, &Bs[(nt+1)&1][0], wave, lane);
      const u16* bb = &Bs[nt&1][0];
      f16x8 bfr[8];
#pragma unroll
      for (int ks = 0; ks < 8; ++ks) bfr[ks] = readB(bb, ks, q, n16);
      f32x4 c0 = {0.f,0.f,0.f,0.f}, c1 = {0.f,0.f,0.f,0.f};
#pragma unroll
      for (int ks = 0; ks < 4; ++ks){
        c0 = mfma16(afr[ks],     bfr[ks],     c0);
        c1 = mfma16(afr[ks + 4], bfr[ks + 4], c1);
      }
#pragma unroll
      for (int r = 0; r < 4; ++r)
        myC[(q*4 + r)*64 + t*16 + n16] = c0[r] + c1[r];
      __syncthreads();
    }
    __asm__ volatile("s_waitcnt lgkmcnt(0)" ::: "memory");
#pragma unroll
    for (int p = 0; p < 2; ++p){
      const int row = p*8 + rbrow;
      const size_t ob = p ? ob1 : ob0;
      f32x4 v0 = *(const f32x4*)&myC[row*64 + seg*8];
      f32x4 v1 = *(const f32x4*)&myC[row*64 + seg*8 + 4];
      if (f32m){
        *(f32x4*)&((float*)Outv)[ob + g4*64 + seg*8]     = v0;
        *(f32x4*)&((float*)Outv)[ob + g4*64 + seg*8 + 4] = v1;
      } else {
        union{ u32 w[4]; u16 h[8]; } pk;
        pk.h[0]=f2b(v0[0]); pk.h[1]=f2b(v0[1]); pk.h[2]=f2b(v0[2]); pk.h[3]=f2b(v0[3]);
        pk.h[4]=f2b(v1[0]); pk.h[5]=f2b(v1[1]); pk.h[6]=f2b(v1[2]); pk.h[7]=f2b(v1[3]);
        *(uint4*)&((u16*)Outv)[ob + g4*64 + seg*8] = *(const uint4*)&pk.w[0];
      }
    }
  }
}

// =========================================================================
// OLD PATH (proven-correct fallback if workspace is too small)
// =========================================================================
__global__ __launch_bounds__(256) void dfab_attn_kernel(
    const void* __restrict__ Xv, const int* __restrict__ Mask,
    const void* __restrict__ Wqkvv, const void* __restrict__ BiasTv,
    const int* __restrict__ RelIdx, u16* __restrict__ Obuf,
    const int* __restrict__ flagp)
{
  __shared__ __align__(16) char lds[59736];
  u16* Ks   = (u16*)(lds);
  u16* Vt   = (u16*)(lds + 19992);
  u16* Wp   = (u16*)(lds + 39192);
  u16* Xs   = (u16*)(lds + 47512);
  u16* Wqt  = (u16*)(lds + 39192);
  u32* Pb   = (u32*)(lds + 55832);
  float* Madd = (float*)(lds + 58264);
  u16* Qb   = (u16*)(lds + 59480);

  const int tid = threadIdx.x;
  const int bx  = blockIdx.x;
  const int win = bx >> 3, h = bx & 7;

  const int f32m = *(const volatile int*)flagp;
  const u16*   Xb = (const u16*)Xv;       const float* Xf = (const float*)Xv;
  const u16*   Wb = (const u16*)Wqkvv;    const float* Wf = (const float*)Wqkvv;
  const u16*   Bb = (const u16*)BiasTv;   const float* Bf = (const float*)BiasTv;

  for (int j = tid; j < 304; j += 256){
    float mv = -1e30f;
    if (j < NTOK){ int l = j / 49, r = j - l * 49;
      mv = (Mask[(win * 49 + r) * 6 + l] != 0) ? 0.0f : -1e30f; }
    Madd[j] = mv;
  }
  for (int idx = tid; idx < 32 * 6; idx += 256){
    int c = idx / 6; Vt[c * VT_STRIDE + NTOK + (idx - c * 6)] = 0;
  }

#pragma unroll 1
  for (int p = 0; p < 4; ++p){
    const int kind = p >> 1;
    const int colbase = 256 + kind * 256 + h * 32 + (p & 1) * 16;
    __syncthreads();
    for (int idx = tid; idx < 16 * 128; idx += 256){
      int c = idx & 15, d2 = idx >> 4;
      float w0, w1;
      if (f32m){ w0 = Wf[(2 * d2) * 768 + colbase + c]; w1 = Wf[(2 * d2 + 1) * 768 + colbase + c]; }
      else     { w0 = b2f(Wb[(2 * d2) * 768 + colbase + c]); w1 = b2f(Wb[(2 * d2 + 1) * 768 + colbase + c]); }
      *(u32*)&Wp[c * WST + 2 * d2] = pack2h(w0, w1);
    }
#pragma unroll 1
    for (int jt = 0; jt < 19; ++jt){
      const int j0 = jt * 16;
      const int nj = (NTOK - j0 < 16) ? (NTOK - j0) : 16;
      __syncthreads();
      for (int idx = tid; idx < nj * 128; idx += 256){
        int jl = idx >> 7, d2 = idx & 127;
        int tok = j0 + jl; int l = tok / 49, r = tok - l * 49;
        size_t off = (size_t)((l * 256 + win) * 49 + r) * 256 + 2 * d2;
        u32 hp;
        if (f32m){ float2 xx = *(const float2*)&Xf[off]; hp = pack2h(xx.x, xx.y); }
        else     { hp = bfp2h(*(const u32*)&Xb[off]); }
        *(u32*)&Xs[jl * WST + 2 * d2] = hp;
      }
      __syncthreads();
      const int jl = tid >> 4, c = tid & 15;
      const u32* xp = (const u32*)&Xs[jl * WST];
      const u32* wp = (const u32*)&Wp[c * WST];
      float a0 = 0.f, a1 = 0.f;
#pragma unroll 4
      for (int d2 = 0; d2 < 128; d2 += 4){
        uint2 xa = *(const uint2*)(xp + d2), xb = *(const uint2*)(xp + d2 + 2);
        uint2 wa = *(const uint2*)(wp + d2), wb = *(const uint2*)(wp + d2 + 2);
        a0 = dot2f(xa.x, wa.x, a0); a1 = dot2f(xa.y, wa.y, a1);
        a0 = dot2f(xb.x, wb.x, a0); a1 = dot2f(xb.y, wb.y, a1);
      }
      if (jl < nj){
        u16 hv = f2h(a0 + a1);
        int tok = j0 + jl;
        if (kind == 0) Ks[tok * KS_STRIDE + (p & 1) * 16 + c] = hv;
        else           Vt[((p & 1) * 16 + c) * VT_STRIDE + tok] = hv;
      }
    }
  }
  __syncthreads();
  for (int idx = tid; idx < 32 * 128; idx += 256){
    int c = idx & 31, d2 = idx >> 5;
    float w0, w1;
    if (f32m){ w0 = Wf[(2 * d2) * 768 + h * 32 + c]; w1 = Wf[(2 * d2 + 1) * 768 + h * 32 + c]; }
    else     { w0 = b2f(Wb[(2 * d2) * 768 + h * 32 + c]); w1 = b2f(Wb[(2 * d2 + 1) * 768 + h * 32 + c]); }
    *(u32*)&Wqt[c * WST + 2 * d2] = pack2h(w0, w1);
  }
  __syncthreads();

  const int wave = tid >> 6, lane = tid & 63;
  const int hf = lane >> 5, c32 = lane & 31;
  u32* mypb = Pb + wave * 152;
  u16* qbw  = Qb + wave * 32;

  for (int i = wave; i < NTOK; i += 4){
    const int li = i / 49, ri = i - li * 49;
    const size_t rowoff = (size_t)((li * 256 + win) * 49 + ri) * 256;
    const u32* wqp = (const u32*)&Wqt[c32 * WST];
    float q0 = 0.f, q1 = 0.f;
    if (f32m){
      const float4* xr4 = (const float4*)&Xf[rowoff];
#pragma unroll 4
      for (int d2 = hf * 64; d2 < hf * 64 + 64; d2 += 2){
        uint2 wq = *(const uint2*)(wqp + d2);
        float4 xx = xr4[d2 >> 1];
        q0 = dot2f(pack2h(xx.x, xx.y), wq.x, q0);
        q1 = dot2f(pack2h(xx.z, xx.w), wq.y, q1);
      }
    } else {
      const u32* xr = (const u32*)&Xb[rowoff];
#pragma unroll 4
      for (int d2 = hf * 64; d2 < hf * 64 + 64; d2 += 2){
        uint2 wq = *(const uint2*)(wqp + d2);
        q0 = dot2f(bfp2h(xr[d2]),     wq.x, q0);
        q1 = dot2f(bfp2h(xr[d2 + 1]), wq.y, q1);
      }
    }
    float qa = q0 + q1;
    qa += __shfl_xor(qa, 32);
    if (hf == 0) qbw[c32] = f2h(qa * 0.17677669529663687f);
    __asm__ volatile("s_waitcnt lgkmcnt(0)" ::: "memory");
    u32 qp[16];
#pragma unroll
    for (int cc = 0; cc < 16; ++cc) qp[cc] = *(const u32*)&qbw[2 * cc];

    float sv[5];
#pragma unroll
    for (int it = 0; it < 5; ++it){
      int j = it * 64 + lane;
      float a;
      if (j < NTOK){
        int nb = RelIdx[i * NTOK + j] * 8 + h;
        float bias = f32m ? Bf[nb] : b2f(Bb[nb]);
        float a0 = bias + Madd[j];
        float a1 = 0.f;
        const u16* kr = &Ks[j * KS_STRIDE];
#pragma unroll
        for (int cc = 0; cc < 16; cc += 2){
          a0 = dot2f(qp[cc],     *(const u32*)&kr[2 * cc],     a0);
          a1 = dot2f(qp[cc + 1], *(const u32*)&kr[2 * cc + 2], a1);
        }
        a = a0 + a1;
      } else a = -3e38f;
      sv[it] = a;
    }
    float m = sv[0];
#pragma unroll
    for (int it = 1; it < 5; ++it) m = fmaxf(m, sv[it]);
    for (int off = 32; off > 0; off >>= 1) m = fmaxf(m, __shfl_xor(m, off));
    float lsum = 0.f;
#pragma unroll
    for (int it = 0; it < 5; ++it){ float e = __expf(sv[it] - m); sv[it] = e; lsum += e; }
    for (int off = 32; off > 0; off >>= 1) lsum += __shfl_xor(lsum, off);
    const float rinv = 1.0f / lsum;
#pragma unroll
    for (int it = 0; it < 5; ++it){
      float pn = sv[it] * rinv;
      float po = __shfl_xor(pn, 1);
      int j = it * 64 + lane;
      if (!(lane & 1) && j < 304) mypb[j >> 1] = pack2h(pn, po);
    }
    __asm__ volatile("s_waitcnt lgkmcnt(0)" ::: "memory");
    const u16* vr = &Vt[c32 * VT_STRIDE];
    const int jb = hf * 148;
    float o0 = 0.f, o1 = 0.f;
#pragma unroll 4
    for (int g = 0; g < 37; ++g){
      int j = jb + 4 * g;
      uint2 vv = *(const uint2*)&vr[j];
      uint2 pp = *(const uint2*)&mypb[j >> 1];
      o0 = dot2f(pp.x, vv.x, o0);
      o1 = dot2f(pp.y, vv.y, o1);
    }
    float o = o0 + o1;
    o += __shfl_xor(o, 32);
    if (hf == 0)
      Obuf[(size_t)(win * NTOK + i) * 256 + h * 32 + c32] = f2b(o);
  }
}

__global__ __launch_bounds__(256) void dfab_proj_kernel(
    const u16* __restrict__ Obuf, const void* __restrict__ Woutv,
    void* __restrict__ Outv, const int* __restrict__ flagp)
{
  __shared__ __align__(16) char lds[33920];
  u16* Ot = (u16*)(lds);
  u16* Wt = (u16*)(lds + 16512);

  const int tid = threadIdx.x;
  const int bx = blockIdx.x;
  const int win = bx / 10, tile = bx - win * 10;
  const int t0 = tile * 32;
  const int nt = (NTOK - t0 < 32) ? (NTOK - t0) : 32;

  const int f32m = *(const volatile int*)flagp;
  const u16* Wob = (const u16*)Woutv; const float* Wof = (const float*)Woutv;

  for (int idx = tid; idx < nt * 128; idx += 256){
    int t = idx >> 7, k2 = idx & 127;
    u32 oo = *(const u32*)&Obuf[(size_t)(win * NTOK + t0 + t) * 256 + 2 * k2];
    *(u32*)&Ot[t * 258 + 2 * k2] = bfp2h(oo);
  }

  float acc[32];
#pragma unroll
  for (int t = 0; t < 32; ++t) acc[t] = 0.f;
  const int dd = tid;

#pragma unroll 1
  for (int kt = 0; kt < 8; ++kt){
    __syncthreads();
    for (int idx = tid; idx < 4096; idx += 256){
      int d = idx & 255, kk2 = idx >> 8;
      int k = kt * 32 + 2 * kk2;
      float w0, w1;
      if (f32m){ w0 = Wof[k * 256 + d]; w1 = Wof[(k + 1) * 256 + d]; }
      else     { w0 = b2f(Wob[k * 256 + d]); w1 = b2f(Wob[(k + 1) * 256 + d]); }
      *(u32*)&Wt[d * 34 + 2 * kk2] = pack2h(w0, w1);
    }
    __syncthreads();
#pragma unroll 2
    for (int kk2 = 0; kk2 < 16; ++kk2){
      u32 wp = *(const u32*)&Wt[dd * 34 + 2 * kk2];
      const u16* orow = &Ot[kt * 32 + 2 * kk2];
#pragma unroll 8
      for (int t = 0; t < 32; ++t){
        u32 op = *(const u32*)&orow[t * 258];
        acc[t] = dot2f(op, wp, acc[t]);
      }
    }
  }

  for (int t = 0; t < nt; ++t){
    int tok = t0 + t; int l = tok / 49, r = tok - l * 49;
    size_t oidx = (size_t)((l * 256 + win) * 49 + r) * 256 + dd;
    if (f32m) ((float*)Outv)[oidx] = acc[t];
    else      ((u16*)Outv)[oidx]   = f2b(acc[t]);
  }
}

// -------------------------------------------------------------------------
extern "C" void kernel_launch(void* const* d_in, const int* in_sizes, int n_in,
                              void* d_out, int out_size, void* d_ws, size_t ws_size,
                              hipStream_t stream) {
  (void)in_sizes; (void)n_in; (void)out_size;
  const void* x          = d_in[0];
  const int*  mask       = (const int*)d_in[1];
  const void* w_qkv      = d_in[2];
  const void* w_out      = d_in[3];
  const void* bias_table = d_in[4];
  const int*  rel_index  = (const int*)d_in[5];
  char* ws = (char*)d_ws;

  if (ws_size >= NEED_WS){
    // MFMA path
    u16* qws   = (u16*)(ws + QWS_OFF);
    u16* kws   = (u16*)(ws + KWS_OFF);
    u16* vws   = (u16*)(ws + VWS_OFF);
    u16* ows   = (u16*)(ws + OWS_OFF);
    float* bsf = (float*)(ws + BIASF_OFF);
    u16* wqt   = (u16*)(ws + WQT_OFF);
    u16* wot   = (u16*)(ws + WOT_OFF);
    int* flag  = (int*)(ws + FLAG2_OFF);
    dfab_probe_kernel<<<1, 64, 0, stream>>>((const u16*)x, flag);
    dfab_prep_kernel<<<3912, 256, 0, stream>>>(w_qkv, w_out, bias_table, rel_index,
                                               wqt, wot, bsf, flag);
    dfab_qkv_kernel<<<1176, 256, 0, stream>>>(x, wqt, qws, kws, vws, flag);
    dfab_attn2_kernel<<<2048, 256, 0, stream>>>(qws, kws, vws, bsf, mask, ows);
    dfab_proj2_kernel<<<1176, 256, 0, stream>>>(ows, wot, d_out, flag);
  } else {
    // fallback: proven dot2 path
    u16* obuf = (u16*)ws;
    int* flag = (int*)(ws + FLAG_OFF);
    dfab_probe_kernel<<<1, 64, 0, stream>>>((const u16*)x, flag);
    dfab_attn_kernel<<<2048, 256, 0, stream>>>(x, mask, w_qkv, bias_table, rel_index, obuf, flag);
    dfab_proj_kernel<<<2560, 256, 0, stream>>>(obuf, w_out, d_out, flag);
  }
}